// Round 2
// baseline (354.111 us; speedup 1.0000x reference)
//
#include <hip/hip_runtime.h>

#define NUM_ENT 64
#define DIM_ENT 8
#define NHID    64
#define NEMB    256
#define BATCH   1024
#define NUM_REL 2016
#define SPLITK  32
#define RPB     63          // relations per block = NUM_REL / SPLITK
#define BM      128         // batch rows per block
#define MB      8           // m-blocks = BATCH / BM

typedef __attribute__((ext_vector_type(8))) short bf16x8;
typedef __attribute__((ext_vector_type(4))) float f32x4;

__device__ __forceinline__ unsigned short f2bf(float f) {
    union { float f; unsigned u; } v; v.f = f;
    unsigned r = v.u + 0x7FFF + ((v.u >> 16) & 1);   // RNE
    return (unsigned short)(r >> 16);
}

// Fused: h = relu(pairs @ W_rel + b_rel) computed per-relation into LDS (bf16),
// then acc += h @ W_fc_slice via MFMA. Split-K partials atomicAdd'ed to out.
__global__ __launch_bounds__(512, 2) void fused_kernel(
    const float* __restrict__ ctx,    // [1024, 512]
    const float* __restrict__ Wrel,   // [16, 64]
    const float* __restrict__ brel,   // [64]
    const float* __restrict__ Wfc,    // [129024, 256]
    float*       __restrict__ out)    // [1024, 256] (pre-zeroed)
{
    const int bid = blockIdx.x;
    const int ks  = bid & (SPLITK - 1);   // k-split chunk (fast-varying -> same-XCD m-duplicates)
    const int mb  = bid >> 5;             // m block 0..7
    const int tid = threadIdx.x;
    const int w   = tid >> 6;             // wave 0..7
    const int l   = tid & 63;             // lane
    const int l15 = l & 15;
    const int kb  = l >> 4;               // 0..3

    __shared__ unsigned short h_lds[2][BM * NHID];   // 2 x 16 KiB, XOR-swizzled rows
    __shared__ int pair_i[RPB], pair_j[RPB];

    // ---- per-block relation (i,j) table
    if (tid < RPB) {
        int rem = ks * RPB + tid;
        int i = 0;
        while (rem >= (NUM_ENT - 1 - i)) { rem -= (NUM_ENT - 1 - i); ++i; }
        pair_i[tid] = i;
        pair_j[tid] = i + 1 + rem;
    }

    // ---- preload W_rel B-fragments (4 hid-subtiles) and b_rel
    // B[k][n]: lane holds n = l15 + 16*ns, k = kb*8 + e (k>=16 -> 0 padding)
    bf16x8 bw[4];
    float  brl[4];
#pragma unroll
    for (int ns = 0; ns < 4; ++ns) {
        const int n = l15 + 16 * ns;
#pragma unroll
        for (int e = 0; e < 8; ++e) {
            const int k = kb * 8 + e;
            const float v = (k < 16) ? Wrel[k * NHID + n] : 0.f;
            bw[ns][e] = (short)f2bf(v);
        }
        brl[ns] = brel[n];
    }

    __syncthreads();   // pair table ready

    f32x4 acc[8][2];   // m_sub 0..7 (16 rows each), local n_sub 0..1
#pragma unroll
    for (int m = 0; m < 8; ++m)
#pragma unroll
        for (int n = 0; n < 2; ++n) acc[m][n] = (f32x4){0.f, 0.f, 0.f, 0.f};

    // h-compute: wave w owns local rows [16w, 16w+16)
    const int row_h = mb * BM + w * 16 + l15;
    const float* __restrict__ ctx_row = ctx + (size_t)row_h * (NUM_ENT * DIM_ENT);

    for (int r = 0; r < RPB; ++r) {
        const int buf = r & 1;
        unsigned short* __restrict__ hb = &h_lds[buf][0];

        // ---------- phase 1: h = relu(pairs @ W_rel + b_rel) for 16 rows ----------
        // A[m][k]: lane row m = l15, k = kb*8+e ; kb=0 -> ents[i], kb=1 -> ents[j], else 0
        bf16x8 ah = {0, 0, 0, 0, 0, 0, 0, 0};
        if (kb < 2) {
            const int ent = (kb == 0) ? pair_i[r] : pair_j[r];
            const float4 v0 = *(const float4*)(ctx_row + ent * DIM_ENT);
            const float4 v1 = *(const float4*)(ctx_row + ent * DIM_ENT + 4);
            ah[0] = (short)f2bf(v0.x); ah[1] = (short)f2bf(v0.y);
            ah[2] = (short)f2bf(v0.z); ah[3] = (short)f2bf(v0.w);
            ah[4] = (short)f2bf(v1.x); ah[5] = (short)f2bf(v1.y);
            ah[6] = (short)f2bf(v1.z); ah[7] = (short)f2bf(v1.w);
        }
#pragma unroll
        for (int ns = 0; ns < 4; ++ns) {
            f32x4 c = {0.f, 0.f, 0.f, 0.f};
            c = __builtin_amdgcn_mfma_f32_16x16x32_bf16(ah, bw[ns], c, 0, 0, 0);
            // C layout: col = l15, row = kb*4 + reg  (verified m89)
#pragma unroll
            for (int reg = 0; reg < 4; ++reg) {
                float hv = c[reg] + brl[ns];
                hv = hv > 0.f ? hv : 0.f;
                const int rr = w * 16 + kb * 4 + reg;       // local row 0..127
                const int cc = l15 + 16 * ns;               // hid 0..63
                int byte = (rr * NHID + cc) * 2;
                byte ^= ((rr & 7) << 4);
                *(unsigned short*)((char*)hb + byte) = f2bf(hv);
            }
        }

        __syncthreads();   // h tile ready (dbuf makes one barrier/iter sufficient)

        // ---------- phase 2: acc += h[128,64] @ Wfc[r*64 : r*64+64, n-strip] ----------
        const float* __restrict__ wf =
            Wfc + (size_t)(ks * RPB + r) * NHID * NEMB;
#pragma unroll
        for (int kh = 0; kh < 2; ++kh) {
            // B frags: lane n = w*32 + ns*16 + l15, k = kh*32 + kb*8 + e (column gather)
            bf16x8 bb[2];
#pragma unroll
            for (int ns = 0; ns < 2; ++ns) {
                const int n = w * 32 + ns * 16 + l15;
                const float* __restrict__ col = wf + (size_t)(kh * 32 + kb * 8) * NEMB + n;
#pragma unroll
                for (int e = 0; e < 8; ++e)
                    bb[ns][e] = (short)f2bf(col[(size_t)e * NEMB]);
            }
#pragma unroll
            for (int m = 0; m < 8; ++m) {
                const int rr = m * 16 + l15;
                int byte = (rr * NHID + kh * 32 + kb * 8) * 2;
                byte ^= ((rr & 7) << 4);
                const bf16x8 aa = *(const bf16x8*)((const char*)hb + byte);
                acc[m][0] = __builtin_amdgcn_mfma_f32_16x16x32_bf16(aa, bb[0], acc[m][0], 0, 0, 0);
                acc[m][1] = __builtin_amdgcn_mfma_f32_16x16x32_bf16(aa, bb[1], acc[m][1], 0, 0, 0);
            }
        }
    }

    // ---------- epilogue: split-K reduction via atomics ----------
#pragma unroll
    for (int m = 0; m < 8; ++m)
#pragma unroll
        for (int ns = 0; ns < 2; ++ns)
#pragma unroll
            for (int reg = 0; reg < 4; ++reg) {
                const int row = mb * BM + m * 16 + kb * 4 + reg;
                const int col = w * 32 + ns * 16 + l15;
                atomicAdd(&out[(size_t)row * NEMB + col], acc[m][ns][reg]);
            }
}

__global__ void bias_relu_kernel(float* __restrict__ out, const float* __restrict__ bfc) {
    const int i = blockIdx.x * 256 + threadIdx.x;   // 65536 threads x float4
    float4 v = ((float4*)out)[i];
    const int c = (i * 4) & (NEMB - 1);
    v.x = fmaxf(v.x + bfc[c + 0], 0.f);
    v.y = fmaxf(v.y + bfc[c + 1], 0.f);
    v.z = fmaxf(v.z + bfc[c + 2], 0.f);
    v.w = fmaxf(v.w + bfc[c + 3], 0.f);
    ((float4*)out)[i] = v;
}

extern "C" void kernel_launch(void* const* d_in, const int* in_sizes, int n_in,
                              void* d_out, int out_size, void* d_ws, size_t ws_size,
                              hipStream_t stream) {
    const float* ctx  = (const float*)d_in[0];
    const float* Wrel = (const float*)d_in[1];
    const float* brel = (const float*)d_in[2];
    const float* Wfc  = (const float*)d_in[3];
    const float* bfc  = (const float*)d_in[4];
    float* out = (float*)d_out;

    hipMemsetAsync(out, 0, (size_t)BATCH * NEMB * sizeof(float), stream);
    fused_kernel<<<MB * SPLITK, 512, 0, stream>>>(ctx, Wrel, brel, Wfc, out);
    bias_relu_kernel<<<(BATCH * NEMB / 4) / 256, 256, 0, stream>>>(out, bfc);
}